// Round 2
// baseline (292.836 us; speedup 1.0000x reference)
//
#include <hip/hip_runtime.h>
#include <hip/hip_bf16.h>
#include <cstdint>

// Problem constants (match reference)
#define B_ 256
#define N_ 131072
#define D_ 256
#define INV_TEMP 20.0f   // 1/0.05
#define EPS_SM 1e-6f
#define EPS_LOG 1e-6f

// GEMM tiling
#define TPB 512          // 8 waves; wave w owns rows w*32..w*32+31
#define BN 128           // cf rows per N-tile
#define BK 64            // K chunk
#define TILES 4          // N-tiles per block; grid = N_/(TILES*BN) = 256 blocks (1/CU)
#define LDB 72           // LDS row stride (elems): 64+8 pad -> 2-way bank aliasing (free)
#define BUFE (BN * LDB)  // 9216 ushorts per buffer
#define NSLOT 32
#define NBLK (N_ / (TILES * BN))  // 256

typedef __bf16 bf16_t;
typedef bf16_t bf16x8 __attribute__((ext_vector_type(8)));
typedef float f32x4 __attribute__((ext_vector_type(4)));

__device__ inline ushort f2bf(float f) {
  uint32_t u = __builtin_bit_cast(uint32_t, f);
  u += 0x7FFFu + ((u >> 16) & 1u);   // round to nearest even
  return (ushort)(u >> 16);
}

struct alignas(16) U8 { ushort u[8]; };

__global__ __launch_bounds__(TPB, 2)
void gemm_rowsum_fused(const float* __restrict__ inp, const float* __restrict__ cf,
                       const int* __restrict__ idx, const int* __restrict__ lab,
                       float* __restrict__ rowsum, unsigned* __restrict__ counter,
                       float* __restrict__ out) {
  __shared__ ushort smem[2 * BUFE];
  __shared__ unsigned done;
  const int tid  = threadIdx.x;
  const int wave = tid >> 6;
  const int lane = tid & 63;
  const int m15  = lane & 15;
  const int q    = lane >> 4;

  const size_t nbase = (size_t)blockIdx.x * (TILES * BN);
  const int brow = tid >> 2, bcg = tid & 3;  // 8192-elem chunk: 4 threads/row x 16 cols
#define LDADDR(c) (cf + (nbase + (size_t)((c) >> 2) * BN + brow) * D_ + ((c) & 3) * BK + bcg * 16)

  // ---- Start the HBM-critical cf stream FIRST (chunks 0 and 1 into registers).
  float4 ldbuf[2][4];  // two in-flight chunks (parity = chunk parity)
#pragma unroll
  for (int i = 0; i < 4; ++i) ldbuf[0][i] = *(const float4*)(LDADDR(0) + i * 4);
#pragma unroll
  for (int i = 0; i < 4; ++i) ldbuf[1][i] = *(const float4*)(LDADDR(1) + i * 4);

  // ---- A fragments straight from global -> registers. Each lane's slice is a
  // contiguous 32 B of inp (L2-resident, 256 KB total); no LDS, no barriers.
  // areg[kc*2+ks][mb]: rows wave*32+mb*16+(lane&15), k = (kc*2+ks)*32 + q*8..+7
  bf16x8 areg[8][2];
#pragma unroll
  for (int kc = 0; kc < 4; ++kc)
#pragma unroll
    for (int ks = 0; ks < 2; ++ks)
#pragma unroll
      for (int mb = 0; mb < 2; ++mb) {
        const float* s = inp + (wave * 32 + mb * 16 + m15) * D_ + kc * BK + ks * 32 + q * 8;
        const float4 v0 = *(const float4*)s;
        const float4 v1 = *(const float4*)(s + 4);
        U8 t;
        t.u[0] = f2bf(v0.x); t.u[1] = f2bf(v0.y); t.u[2] = f2bf(v0.z); t.u[3] = f2bf(v0.w);
        t.u[4] = f2bf(v1.x); t.u[5] = f2bf(v1.y); t.u[6] = f2bf(v1.z); t.u[7] = f2bf(v1.w);
        areg[kc * 2 + ks][mb] = __builtin_bit_cast(bf16x8, t);
      }

  f32x4 acc[2][8];
  float rs[2][4];
#pragma unroll
  for (int mb = 0; mb < 2; ++mb) {
#pragma unroll
    for (int nb = 0; nb < 8; ++nb) acc[mb][nb] = (f32x4){0.f, 0.f, 0.f, 0.f};
#pragma unroll
    for (int r = 0; r < 4; ++r) rs[mb][r] = 0.f;
  }

  // Chunk 0 -> buf 0 (loads already issued above; convert + LDS write).
  {
    ushort* dst = &smem[brow * LDB + bcg * 16];
#pragma unroll
    for (int i = 0; i < 4; ++i) {
      const float4 v = ldbuf[0][i];
      U8 w;
      w.u[0] = f2bf(v.x); w.u[1] = f2bf(v.y); w.u[2] = f2bf(v.z); w.u[3] = f2bf(v.w);
      *(ushort4*)(dst + i * 4) = *(const ushort4*)&w.u[0];
    }
  }

  // ---- Steady state: 16 chunks (tile=c>>2, kc=c&3), prefetch distance 2.
#pragma unroll
  for (int c = 0; c < TILES * 4; ++c) {
    __syncthreads();  // buf[c&1] ready; prior reads of buf[(c+1)&1] drained
    if (c + 2 < TILES * 4) {
#pragma unroll
      for (int i = 0; i < 4; ++i) ldbuf[c & 1][i] = *(const float4*)(LDADDR(c + 2) + i * 4);
    }
    const ushort* bs = &smem[(c & 1) * BUFE];
#pragma unroll
    for (int ks = 0; ks < 2; ++ks) {
      bf16x8 bfr[8];
#pragma unroll
      for (int nb = 0; nb < 8; ++nb)
        bfr[nb] = __builtin_bit_cast(
            bf16x8, *(const uint4*)(&bs[(nb * 16 + m15) * LDB + ks * 32 + q * 8]));
#pragma unroll
      for (int mb = 0; mb < 2; ++mb)
#pragma unroll
        for (int nb = 0; nb < 8; ++nb)
          acc[mb][nb] = __builtin_amdgcn_mfma_f32_16x16x32_bf16(
              areg[(c & 3) * 2 + ks][mb], bfr[nb], acc[mb][nb], 0, 0, 0);
    }
    if ((c & 3) == 3) {  // tile finished: fold exp into register row-sums
#pragma unroll
      for (int mb = 0; mb < 2; ++mb)
#pragma unroll
        for (int nb = 0; nb < 8; ++nb)
#pragma unroll
          for (int r = 0; r < 4; ++r)
            rs[mb][r] += __expf(acc[mb][nb][r] * INV_TEMP);
      if (c + 1 < TILES * 4) {
#pragma unroll
        for (int mb = 0; mb < 2; ++mb)
#pragma unroll
          for (int nb = 0; nb < 8; ++nb) acc[mb][nb] = (f32x4){0.f, 0.f, 0.f, 0.f};
      }
    }
    if (c + 1 < TILES * 4) {  // convert+write chunk c+1 (loads landed long ago)
      ushort* dst = &smem[((c + 1) & 1) * BUFE + brow * LDB + bcg * 16];
#pragma unroll
      for (int i = 0; i < 4; ++i) {
        const float4 v = ldbuf[(c + 1) & 1][i];
        U8 w;
        w.u[0] = f2bf(v.x); w.u[1] = f2bf(v.y); w.u[2] = f2bf(v.z); w.u[3] = f2bf(v.w);
        *(ushort4*)(dst + i * 4) = *(const ushort4*)&w.u[0];
      }
    }
  }

  // C/D layout: col = lane&15, row = wave*32 + mb*16 + q*4 + r. Reduce the 16
  // lanes of each quad, then one atomic batch per wave.
#pragma unroll
  for (int off = 8; off >= 1; off >>= 1)
#pragma unroll
    for (int mb = 0; mb < 2; ++mb)
#pragma unroll
      for (int r = 0; r < 4; ++r)
        rs[mb][r] += __shfl_xor(rs[mb][r], off, 64);

  if (m15 == 0) {
    float* slot = rowsum + (blockIdx.x & (NSLOT - 1)) * B_;
#pragma unroll
    for (int mb = 0; mb < 2; ++mb)
#pragma unroll
      for (int r = 0; r < 4; ++r)
        atomicAdd(&slot[wave * 32 + mb * 16 + q * 4 + r], rs[mb][r]);
  }
#undef LDADDR

  // ---- Fused finalize: last block to finish computes the loss.
  __syncthreads();  // drains this block's atomics (vmcnt(0) before s_barrier)
  if (tid == 0) {
    __threadfence();  // make this block's rowsum atomics device-visible first
    const unsigned prev = __hip_atomic_fetch_add(counter, 1u, __ATOMIC_ACQ_REL,
                                                 __HIP_MEMORY_SCOPE_AGENT);
    done = (prev == (unsigned)(gridDim.x - 1)) ? 1u : 0u;
  }
  __syncthreads();
  if (done) {
    __threadfence();  // acquire side: order counter observation before rowsum reads
    float* red = (float*)smem;  // reuse LDS: [0,512) dot partials, [512,768) log terms
    const int b = tid >> 1, part = tid & 1;
    const int t = lab[idx[b]];
    const float4* a4 = (const float4*)(inp + b * D_ + part * 128);
    const float4* c4 = (const float4*)(cf + (size_t)t * D_ + part * 128);
    float dot = 0.f;
#pragma unroll
    for (int i = 0; i < 32; ++i) {
      const float4 x = a4[i], y = c4[i];
      dot += x.x * y.x + x.y * y.y + x.z * y.z + x.w * y.w;
    }
    red[tid] = dot;
    __syncthreads();
    if (tid < 256) {
      const float d = red[2 * tid] + red[2 * tid + 1];
      float S = 0.f;
#pragma unroll
      for (int s = 0; s < NSLOT; ++s)
        S += __hip_atomic_load(&rowsum[s * B_ + tid], __ATOMIC_RELAXED,
                               __HIP_MEMORY_SCOPE_AGENT);
      red[512 + tid] = __logf(__expf(d * INV_TEMP) / (S + EPS_SM) + EPS_LOG);
    }
    __syncthreads();
    for (int off = 128; off >= 1; off >>= 1) {
      if (tid < off) red[512 + tid] += red[512 + tid + off];
      __syncthreads();
    }
    if (tid == 0) out[0] = -red[512] * (1.0f / 256.0f);
  }
}

extern "C" void kernel_launch(void* const* d_in, const int* in_sizes, int n_in,
                              void* d_out, int out_size, void* d_ws, size_t ws_size,
                              hipStream_t stream) {
  const float* inp = (const float*)d_in[0];  // inputs [256,256]
  const float* cf  = (const float*)d_in[1];  // cluster_features [131072,256]
  // d_in[2] = instance_features: unused by the reference
  const int* idx = (const int*)d_in[3];      // indexes [256]
  const int* lab = (const int*)d_in[4];      // labels [131072]
  float* out = (float*)d_out;
  float* rowsum = (float*)d_ws;              // NSLOT * 256 floats
  unsigned* counter = (unsigned*)(rowsum + NSLOT * B_);

  hipMemsetAsync(d_ws, 0, (NSLOT * B_ + 16) * sizeof(float), stream);
  gemm_rowsum_fused<<<dim3(NBLK), dim3(TPB), 0, stream>>>(inp, cf, idx, lab,
                                                          rowsum, counter, out);
}